// Round 9
// baseline (340.586 us; speedup 1.0000x reference)
//
#include <hip/hip_runtime.h>
#include <cmath>

typedef unsigned short u16;
typedef float floatx4 __attribute__((ext_vector_type(4)));
typedef short short8 __attribute__((ext_vector_type(8)));
typedef short short4v __attribute__((ext_vector_type(4)));
typedef __bf16 bf16x8 __attribute__((ext_vector_type(8)));

#define GLOBAL_AS __attribute__((address_space(1)))
#define LDS_AS __attribute__((address_space(3)))

#define S_LEN 2048
#define D_MODEL 2048
#define NH 16
#define NKV 4
#define DHEAD 128
#define SM_SCALE 0.08838834764831843f
#define K2 (SM_SCALE * 1.4426950408889634f) /* SM_SCALE * log2(e) */

__device__ __forceinline__ u16 f2bf(float f) {
    unsigned int u = __builtin_bit_cast(unsigned int, f);
    u += 0x7fffu + ((u >> 16) & 1u);
    return (u16)(u >> 16);
}
__device__ __forceinline__ u16 f2bfr(float f) {
    unsigned int u = __builtin_bit_cast(unsigned int, f);
    return (u16)((u + 0x8000u) >> 16);
}
__device__ __forceinline__ float bf2f(u16 x) {
    unsigned int u = ((unsigned int)x) << 16;
    return __builtin_bit_cast(float, u);
}
__device__ __forceinline__ floatx4 zf4() {
    floatx4 z; z[0] = 0.f; z[1] = 0.f; z[2] = 0.f; z[3] = 0.f; return z;
}
__device__ __forceinline__ floatx4 mfma16(short8 a, short8 b, floatx4 c) {
    return __builtin_amdgcn_mfma_f32_16x16x32_bf16(
        __builtin_bit_cast(bf16x8, a), __builtin_bit_cast(bf16x8, b), c, 0, 0, 0);
}
__device__ __forceinline__ floatx4 mfma16k16(short4v a, short4v b, floatx4 c) {
    return __builtin_amdgcn_mfma_f32_16x16x16bf16_1k(a, b, c, 0, 0, 0);
}
__device__ __forceinline__ void async16(const u16* g, u16* l) {
    __builtin_amdgcn_global_load_lds((GLOBAL_AS void*)g, (LDS_AS void*)l, 16, 0, 0);
}

// ---------------- cast X fp32 -> bf16, plus rope tables (fused: one launch) ----------------
__global__ void cast_tables_kernel(const float4* __restrict__ in, ushort4* __restrict__ out,
                                   float* __restrict__ cs_tab, float* __restrict__ sn_tab) {
    int bid = blockIdx.x;
    if (bid < 8192) {
        int i = bid * 256 + threadIdx.x;
        float4 v = in[i];
        ushort4 o;
        o.x = f2bf(v.x); o.y = f2bf(v.y); o.z = f2bf(v.z); o.w = f2bf(v.w);
        out[i] = o;
    } else {
        int idx = (bid - 8192) * 256 + threadIdx.x;  // 2048*64
        int p = idx >> 6, jj = idx & 63;
        double e = (double)(2 * jj) / 128.0;
        double invf = pow(10000.0, -e);
        float arg = (float)p * (float)invf;  // match reference's fp32 angle
        cs_tab[idx] = (float)cos((double)arg);
        sn_tab[idx] = (float)sin((double)arg);
    }
}

// ---------------- transpose + cast all 4 weights in one launch ----------------
__global__ void transpose_all_kernel(const float* __restrict__ wq, const float* __restrict__ wk,
                                     const float* __restrict__ wv, const float* __restrict__ wo,
                                     u16* __restrict__ Wqkv, u16* __restrict__ Wo) {
    __shared__ float tile[32][33];
    int x = blockIdx.x;
    const float* in; u16* out; int C, bx;
    if (x < 64)      { in = wq; out = Wqkv;                     C = 2048; bx = x * 32; }
    else if (x < 80) { in = wk; out = Wqkv + (size_t)2048*2048; C = 512;  bx = (x - 64) * 32; }
    else if (x < 96) { in = wv; out = Wqkv + (size_t)2560*2048; C = 512;  bx = (x - 80) * 32; }
    else             { in = wo; out = Wo;                       C = 2048; bx = (x - 96) * 32; }
    const int R = 2048;
    int tx = threadIdx.x & 31, ty = threadIdx.x >> 5;
    int by = blockIdx.y * 32;  // over R
#pragma unroll
    for (int i = 0; i < 32; i += 8)
        tile[ty + i][tx] = in[(size_t)(by + ty + i) * C + bx + tx];
    __syncthreads();
#pragma unroll
    for (int i = 0; i < 32; i += 8)
        out[(size_t)(bx + ty + i) * R + by + tx] = f2bf(tile[tx][ty + i]);
}

// ---------------- apply RoPE in place on K only (Q rope is fused into fa) ----------------
__global__ void rope_k_kernel(u16* __restrict__ Kb, const int* __restrict__ pos,
                              const float4* __restrict__ cs_tab,
                              const float4* __restrict__ sn_tab) {
    int idx = blockIdx.x * 256 + threadIdx.x;  // 2*4*2048*16 = 262144
    int j4 = idx & 15;
    int s = (idx >> 4) & 2047;
    int r = idx >> 15;        // b*4 + hh
    int hh = r & 3, b = r >> 2;
    int p = pos[b * S_LEN + s];
    float4 cs = cs_tab[p * 16 + j4];
    float4 sn = sn_tab[p * 16 + j4];
    u16* base = Kb + (((size_t)(b * NKV + hh)) * S_LEN + s) * DHEAD + j4 * 4;
    ushort4 a = *(const ushort4*)(base);
    ushort4 c = *(const ushort4*)(base + 64);
    ushort4 oa, oc;
    float x1, x2;
    x1 = bf2f(a.x); x2 = bf2f(c.x); oa.x = f2bf(x1 * cs.x - x2 * sn.x); oc.x = f2bf(x2 * cs.x + x1 * sn.x);
    x1 = bf2f(a.y); x2 = bf2f(c.y); oa.y = f2bf(x1 * cs.y - x2 * sn.y); oc.y = f2bf(x2 * cs.y + x1 * sn.y);
    x1 = bf2f(a.z); x2 = bf2f(c.z); oa.z = f2bf(x1 * cs.z - x2 * sn.z); oc.z = f2bf(x2 * cs.z + x1 * sn.z);
    x1 = bf2f(a.w); x2 = bf2f(c.w); oa.w = f2bf(x1 * cs.w - x2 * sn.w); oc.w = f2bf(x2 * cs.w + x1 * sn.w);
    *(ushort4*)(base) = oa;
    *(ushort4*)(base + 64) = oc;
}

// ---------------- 4-phase deep-pipelined GEMM mainloop (m201-derived; BK=64, 8 waves 2Mx4N) ----------------
// BM = M_REP*32 (256 qkv / 128 out); BN = 256.  Per K-tile:
//   P0: stage ENTIRE tile kt+1 -> buf[nxt] (TLOADS loads/thread, full-tile cover);
//       s_waitcnt vmcnt(TLOADS)  <- retires exactly tile kt's TLOADS (issued one
//       full tile ago, fully covered), keeps kt+1's in flight (counted, never 0);
//       s_barrier  <- tile kt now visible to ALL waves (r8 bug: ds_read before
//       this barrier raced other waves' in-flight loads);
//       ds_read bf[0..1]+af[half0]; bar; MFMA Q(0,0); bar.
//   P1: ds_read bf[2..3]; bar; MFMA Q(0,1); bar.
//   P2: ds_read af[half1]; bar; MFMA Q(1,0); bar.
//   P3: MFMA Q(1,1); bar  <- end-of-tile: all reads of buf[cur] done before
//       tile kt+1's P0 stages overwrite it.
// bf held across the tile; af per m-half (overwritten at P2 after last use P1).
// XOR-chunk swizzle (slot s holds chunk s^(row&7)): linear LDS dest +
// pre-swizzled global source + swizzled ds_read (guide rule 21 pattern).
template <int M_REP>
__device__ __forceinline__ void gemm_8ph(const u16* __restrict__ A,
                                         const u16* __restrict__ Bt, int K,
                                         u16* ldsA, u16* ldsB,
                                         floatx4 acc[M_REP][4]) {
    constexpr int BM = M_REP * 32;
    constexpr int ALOADS = BM / 64;      // A gloads/thread per tile (4 qkv, 2 out)
    const int t = threadIdx.x;
    const int lane = t & 63, wave = t >> 6;
    const int wr = wave >> 2, wc = wave & 3;
    const int lr = lane & 15, q = lane >> 4;
    const int swz = lr & 7;
    const int m0 = blockIdx.y * BM, n0 = blockIdx.x * 256;

#pragma unroll
    for (int r = 0; r < M_REP; ++r)
#pragma unroll
        for (int c = 0; c < 4; ++c) acc[r][c] = zf4();

    auto stageT = [&](int kt, int bs) {  // full tile: A then B
#pragma unroll
        for (int i = 0; i < ALOADS; ++i) {
            int ci = i * 512 + t;
            int grow = ci >> 3;
            int kc = ((ci & 7) ^ (grow & 7)) << 3;
            async16(A + (size_t)(m0 + grow) * K + kt * 64 + kc,
                    ldsA + bs * (BM * 64) + (i * 512 + wave * 64) * 8);
        }
#pragma unroll
        for (int i = 0; i < 4; ++i) {
            int ci = i * 512 + t;
            int grow = ci >> 3;
            int kc = ((ci & 7) ^ (grow & 7)) << 3;
            async16(Bt + (size_t)(n0 + grow) * K + kt * 64 + kc,
                    ldsB + bs * (256 * 64) + (i * 512 + wave * 64) * 8);
        }
    };

    const int NT = K / 64;
    stageT(0, 0);

    for (int kt = 0; kt < NT; ++kt) {
        const int cur = kt & 1, nxt = cur ^ 1;
        const int kn = (kt + 1 < NT) ? kt + 1 : 0;  // dummy re-stage on last tile
        const u16* la = ldsA + cur * (BM * 64);
        const u16* lb = ldsB + cur * (256 * 64);
        short8 af[M_REP / 2][2], bf[4][2];

        // ---- P0 ----
        stageT(kn, nxt);
        if constexpr (M_REP == 8) asm volatile("s_waitcnt vmcnt(8)" ::: "memory");
        else                      asm volatile("s_waitcnt vmcnt(6)" ::: "memory");
        __builtin_amdgcn_s_barrier();  // tile kt visible to all waves
#pragma unroll
        for (int nf = 0; nf < 2; ++nf)
#pragma unroll
            for (int ks = 0; ks < 2; ++ks)
                bf[nf][ks] = *(const short8*)(lb + (wc * 64 + nf * 16 + lr) * 64 +
                                              (((ks * 4 + q) ^ swz) << 3));
#pragma unroll
        for (int mf = 0; mf < M_REP / 2; ++mf)
#pragma unroll
            for (int ks = 0; ks < 2; ++ks)
                af[mf][ks] = *(const short8*)(la + (wr * (M_REP * 16) + mf * 16 + lr) * 64 +
                                              (((ks * 4 + q) ^ swz) << 3));
        __builtin_amdgcn_s_barrier();
        __builtin_amdgcn_s_setprio(1);
#pragma unroll
        for (int mf = 0; mf < M_REP / 2; ++mf)
#pragma unroll
            for (int nf = 0; nf < 2; ++nf)
#pragma unroll
                for (int ks = 0; ks < 2; ++ks)
                    acc[mf][nf] = mfma16(af[mf][ks], bf[nf][ks], acc[mf][nf]);
        __builtin_amdgcn_s_setprio(0);
        __builtin_amdgcn_s_barrier();

        // ---- P1 ----
#pragma unroll
        for (int nf = 0; nf < 2; ++nf)
#pragma unroll
            for (int ks = 0; ks < 2; ++ks)
                bf[2 + nf][ks] = *(const short8*)(lb + (wc * 64 + (2 + nf) * 16 + lr) * 64 +
                                                  (((ks * 4 + q) ^ swz) << 3));
        __builtin_amdgcn_s_barrier();
        __builtin_amdgcn_s_setprio(1);
#pragma unroll
        for (int mf = 0; mf < M_REP / 2; ++mf)
#pragma unroll
            for (int nf = 2; nf < 4; ++nf)
#pragma unroll
                for (int ks = 0; ks < 2; ++ks)
                    acc[mf][nf] = mfma16(af[mf][ks], bf[nf][ks], acc[mf][nf]);
        __builtin_amdgcn_s_setprio(0);
        __builtin_amdgcn_s_barrier();

        // ---- P2 ----
#pragma unroll
        for (int mf = 0; mf < M_REP / 2; ++mf)
#pragma unroll
            for (int ks = 0; ks < 2; ++ks)
                af[mf][ks] = *(const short8*)(la + (wr * (M_REP * 16) +
                                              (M_REP / 2 + mf) * 16 + lr) * 64 +
                                              (((ks * 4 + q) ^ swz) << 3));
        __builtin_amdgcn_s_barrier();
        __builtin_amdgcn_s_setprio(1);
#pragma unroll
        for (int mf = 0; mf < M_REP / 2; ++mf)
#pragma unroll
            for (int nf = 0; nf < 2; ++nf)
#pragma unroll
                for (int ks = 0; ks < 2; ++ks)
                    acc[M_REP / 2 + mf][nf] =
                        mfma16(af[mf][ks], bf[nf][ks], acc[M_REP / 2 + mf][nf]);
        __builtin_amdgcn_s_setprio(0);
        __builtin_amdgcn_s_barrier();

        // ---- P3 ----
        __builtin_amdgcn_s_setprio(1);
#pragma unroll
        for (int mf = 0; mf < M_REP / 2; ++mf)
#pragma unroll
            for (int nf = 2; nf < 4; ++nf)
#pragma unroll
                for (int ks = 0; ks < 2; ++ks)
                    acc[M_REP / 2 + mf][nf] =
                        mfma16(af[mf][ks], bf[nf][ks], acc[M_REP / 2 + mf][nf]);
        __builtin_amdgcn_s_setprio(0);
        __builtin_amdgcn_s_barrier();  // end-of-tile: buf[cur] reads complete
    }
    asm volatile("s_waitcnt vmcnt(0)" ::: "memory");  // drain dummy loads
}

// ---------------- QKV GEMM (256x256): scatter epilogue into Q/K/V^T ----------------
__global__ __launch_bounds__(512, 1) void qkv_gemm_kernel(const u16* __restrict__ A,
                                                          const u16* __restrict__ Bt,
                                                          u16* __restrict__ Qb,
                                                          u16* __restrict__ Kb,
                                                          u16* __restrict__ Vt) {
    __shared__ u16 ldsA[2 * 256 * 64];
    __shared__ u16 ldsB[2 * 256 * 64];
    floatx4 acc[8][4];
    gemm_8ph<8>(A, Bt, D_MODEL, ldsA, ldsB, acc);

    const int t = threadIdx.x, lane = t & 63, wave = t >> 6;
    const int wr = wave >> 2, wc = wave & 3, lr = lane & 15, q = lane >> 4;
    const int m0 = blockIdx.y * 256 + wr * 128, n0 = blockIdx.x * 256 + wc * 64;
#pragma unroll
    for (int r = 0; r < 8; ++r)
#pragma unroll
        for (int c = 0; c < 4; ++c) {
            int gc = n0 + c * 16 + lr;
#pragma unroll
            for (int rr = 0; rr < 4; ++rr) {
                int grow = m0 + r * 16 + q * 4 + rr;  // token
                int bb = grow >> 11, s = grow & 2047;
                u16 bv = f2bf(acc[r][c][rr]);
                int d = gc & 127;
                if (gc < 2048) {
                    int hh = gc >> 7;
                    Qb[(((size_t)(bb * NH + hh)) * S_LEN + s) * DHEAD + d] = bv;
                } else if (gc < 2560) {
                    int hh = (gc - 2048) >> 7;
                    Kb[(((size_t)(bb * NKV + hh)) * S_LEN + s) * DHEAD + d] = bv;
                } else {
                    int hh = (gc - 2560) >> 7;
                    int s2 = s ^ ((d & 8) >> 1);  // V half-spread (fa's b64 V reads)
                    Vt[(((size_t)(bb * NKV + hh)) * DHEAD + d) * S_LEN + s2] = bv;
                }
            }
        }
}

// ---------------- out GEMM (128x256 -> grid 8x32 = 256 = 1 block/CU) ----------------
__global__ __launch_bounds__(512, 1) void out_gemm_kernel(const u16* __restrict__ A,
                                                          const u16* __restrict__ Bt,
                                                          float* __restrict__ out) {
    __shared__ u16 ldsA[2 * 128 * 64];
    __shared__ u16 ldsB[2 * 256 * 64];
    floatx4 acc[4][4];
    gemm_8ph<4>(A, Bt, D_MODEL, ldsA, ldsB, acc);

    const int t = threadIdx.x, lane = t & 63, wave = t >> 6;
    const int wr = wave >> 2, wc = wave & 3, lr = lane & 15, q = lane >> 4;
    const int m0 = blockIdx.y * 128 + wr * 64, n0 = blockIdx.x * 256 + wc * 64;
#pragma unroll
    for (int r = 0; r < 4; ++r)
#pragma unroll
        for (int c = 0; c < 4; ++c) {
            int gc = n0 + c * 16 + lr;
#pragma unroll
            for (int rr = 0; rr < 4; ++rr) {
                int grow = m0 + r * 16 + q * 4 + rr;
                out[(size_t)grow * D_MODEL + gc] = acc[r][c][rr];
            }
        }
}

// ---------------- flash attention (r3 version, best measured: 85.2 us) ----------------
__global__ __launch_bounds__(256, 2) void fa_kernel(const u16* __restrict__ Qb,
                                                    const u16* __restrict__ Kb,
                                                    const u16* __restrict__ Vt,
                                                    u16* __restrict__ Ob,
                                                    const int* __restrict__ pos,
                                                    const float4* __restrict__ cs_tab,
                                                    const float4* __restrict__ sn_tab) {
    __shared__ u16 ldsK[2][64 * 128];
    __shared__ u16 ldsV[2][128 * 64];

    const int t = threadIdx.x, lane = t & 63, wave = t >> 6;
    const int lr = lane & 15, q = lane >> 4;
    const int swz = lr & 7;

    const int bid = blockIdx.x;
    const int bh = bid >> 4, p = bid & 15;
    const int qt0 = p, qt1 = 31 - p;
    const int b = bh >> 4, h = bh & 15;
    const int kvh = h >> 2;

    const u16* Kp = Kb + (size_t)(b * NKV + kvh) * S_LEN * DHEAD;
    const u16* Vp = Vt + (size_t)(b * NKV + kvh) * DHEAD * S_LEN;

    short8 qf0[4], qf1[4];
    auto load_rope_q = [&](int qt, short8 (&qf)[4]) {
        const u16* Qp = Qb + ((size_t)((b * NH + h) * S_LEN) + qt * 64 + wave * 16) * DHEAD;
#pragma unroll
        for (int kk = 0; kk < 4; ++kk)
            qf[kk] = *(const short8*)(Qp + (size_t)lr * DHEAD + kk * 32 + q * 8);
        const int srow = qt * 64 + wave * 16 + lr;
        const int pp = pos[b * S_LEN + srow];
#pragma unroll
        for (int kk = 0; kk < 2; ++kk)
#pragma unroll
            for (int h4 = 0; h4 < 2; ++h4) {
                float4 cs = cs_tab[pp * 16 + kk * 8 + q * 2 + h4];
                float4 sn = sn_tab[pp * 16 + kk * 8 + q * 2 + h4];
#pragma unroll
                for (int e = 0; e < 4; ++e) {
                    float cc = (&cs.x)[e], ss = (&sn.x)[e];
                    int ei = h4 * 4 + e;
                    float x1 = bf2f((u16)qf[kk][ei]);
                    float x2 = bf2f((u16)qf[kk + 2][ei]);
                    qf[kk][ei]     = (short)f2bf(x1 * cc - x2 * ss);
                    qf[kk + 2][ei] = (short)f2bf(x2 * cc + x1 * ss);
                }
            }
    };
    load_rope_q(qt0, qf0);
    load_rope_q(qt1, qf1);

    auto stage = [&](int kt, int bs) {
#pragma unroll
        for (int i = 0; i < 4; ++i) {
            int ci = i * 256 + t;
            int krow = ci >> 4, kc = ((ci & 15) ^ ((ci >> 4) & 7)) << 3;
            async16(Kp + (size_t)(kt * 64 + krow) * DHEAD + kc,
                    &ldsK[bs][(i * 256 + wave * 64) * 8]);
            int dh = ci >> 3, vc = ((ci & 7) ^ ((ci >> 3) & 7)) << 3;
            async16(Vp + (size_t)dh * S_LEN + kt * 64 + vc,
                    &ldsV[bs][(i * 256 + wave * 64) * 8]);
        }
    };

    floatx4 accO[8];
    float m_i, l_i;

    auto do_tile = [&](int kt, int qt_c, const short8 (&qfc)[4], int bs) {
        floatx4 sc[4];
        __builtin_amdgcn_s_setprio(1);
#pragma unroll
        for (int c = 0; c < 4; ++c) {
            sc[c] = zf4();
#pragma unroll
            for (int kk = 0; kk < 4; ++kk) {
                short8 kfr = *(const short8*)(&ldsK[bs][(c * 16 + lr) * DHEAD +
                                              (((kk * 4 + q) ^ swz) << 3)]);
                sc[c] = mfma16(kfr, qfc[kk], sc[c]);
            }
        }
        __builtin_amdgcn_s_setprio(0);

        if (kt == qt_c) {
            const int qrow = wave * 16 + lr;
#pragma unroll
            for (int c = 0; c < 4; ++c)
#pragma unroll
                for (int rr = 0; rr < 4; ++rr)
                    if (c * 16 + q * 4 + rr > qrow) sc[c][rr] = -3e38f;
        }

        float mx = -3e38f;
#pragma unroll
        for (int c = 0; c < 4; ++c)
#pragma unroll
            for (int rr = 0; rr < 4; ++rr) mx = fmaxf(mx, sc[c][rr]);
        mx = fmaxf(mx, __shfl_xor(mx, 16));
        mx = fmaxf(mx, __shfl_xor(mx, 32));
        float mnew = fmaxf(m_i, mx);
        float mk = mnew * K2;
        bool anyup = __any(mnew > m_i);
        float rs = 0.f;
#pragma unroll
        for (int c = 0; c < 4; ++c)
#pragma unroll
            for (int rr = 0; rr < 4; ++rr) {
                float pe = __builtin_amdgcn_exp2f(fmaf(sc[c][rr], K2, -mk));
                sc[c][rr] = pe;
                rs += pe;
            }
        rs += __shfl_xor(rs, 16);
        rs += __shfl_xor(rs, 32);
        if (anyup) {
            float alpha = __builtin_amdgcn_exp2f(fmaf(m_i, K2, -mk));
            l_i = l_i * alpha + rs;
#pragma unroll
            for (int d = 0; d < 8; ++d) accO[d] *= alpha;
        } else {
            l_i += rs;
        }
        m_i = mnew;

        short4v pb[4];
#pragma unroll
        for (int c = 0; c < 4; ++c) {
            pb[c][0] = (short)f2bfr(sc[c][0]);
            pb[c][1] = (short)f2bfr(sc[c][1]);
            pb[c][2] = (short)f2bfr(sc[c][2]);
            pb[c][3] = (short)f2bfr(sc[c][3]);
        }

        __builtin_amdgcn_s_setprio(1);
#pragma unroll
        for (int ks = 0; ks < 4; ++ks)
#pragma unroll
            for (int d = 0; d < 8; ++d) {
                short4v vf = *(const short4v*)(&ldsV[bs][(d * 16 + lr) * 64 +
                                               (((ks * 2 + (q >> 1)) ^ swz) << 3) +
                                               (((q ^ (lr >> 3)) & 1) << 2)]);
                accO[d] = mfma16k16(vf, pb[ks], accO[d]);
            }
        __builtin_amdgcn_s_setprio(0);
    };

    auto epilogue = [&](int qt_c) {
        const int tok = qt_c * 64 + wave * 16 + lr;
        const float inv = 1.0f / l_i;
        u16* orow = Ob + ((size_t)(b * S_LEN + tok)) * (NH * DHEAD) + h * DHEAD + q * 4;
#pragma unroll
        for (int d = 0; d < 8; ++d) {
            ushort4 o;
            o.x = f2bf(accO[d][0] * inv);
            o.y = f2bf(accO[d][1] * inv);
            o.z = f2bf(accO[d][2] * inv);
            o.w = f2bf(accO[d][3] * inv);
            *(ushort4*)(orow + d * 16) = o;
        }
    };

#pragma unroll
    for (int d = 0; d < 8; ++d) accO[d] = zf4();
    m_i = -3e38f; l_i = 0.f;

    int cur = 0;
    stage(0, 0);
    __syncthreads();

    for (int kt = 0; kt <= qt0; ++kt) {
        int nxt = cur ^ 1;
        int nk = (kt < qt0) ? kt + 1 : 0;  // last tile prefetches seg-1 kt=0
        stage(nk, nxt);
        do_tile(kt, qt0, qf0, cur);
        __syncthreads();
        cur = nxt;
    }
    epilogue(qt0);
#pragma unroll
    for (int d = 0; d < 8; ++d) accO[d] = zf4();
    m_i = -3e38f; l_i = 0.f;

    for (int kt = 0; kt <= qt1; ++kt) {
        int nxt = cur ^ 1;
        if (kt < qt1) stage(kt + 1, nxt);
        do_tile(kt, qt1, qf1, cur);
        __syncthreads();
        cur = nxt;
    }
    epilogue(qt1);
}

extern "C" void kernel_launch(void* const* d_in, const int* in_sizes, int n_in,
                              void* d_out, int out_size, void* d_ws, size_t ws_size,
                              hipStream_t stream) {
    const float* X  = (const float*)d_in[0];
    const int* pos  = (const int*)d_in[1];
    const float* wq = (const float*)d_in[2];
    const float* wk = (const float*)d_in[3];
    const float* wv = (const float*)d_in[4];
    const float* wo = (const float*)d_in[5];
    float* out = (float*)d_out;

    char* w = (char*)d_ws;
    u16* Xbf    = (u16*)(w);                    // 4096*2048*2      = 16777216
    u16* Wqkv   = (u16*)(w + 16777216);         // 3072*2048*2      = 12582912
    u16* Wo     = (u16*)(w + 29360128);         // 2048*2048*2      =  8388608
    u16* Qb     = (u16*)(w + 37748736);         // 2*16*2048*128*2  = 16777216
    u16* Kb     = (u16*)(w + 54525952);         // 2*4*2048*128*2   =  4194304
    u16* Vt     = (u16*)(w + 58720256);         //                  =  4194304
    u16* Ob     = (u16*)(w + 62914560);         // 4096*2048*2      = 16777216
    float* cst  = (float*)(w + 79691776);       // 2048*64*4        =   524288
    float* snt  = (float*)(w + 80216064);       //                  =   524288

    cast_tables_kernel<<<8704, 256, 0, stream>>>((const float4*)X, (ushort4*)Xbf, cst, snt);
    transpose_all_kernel<<<dim3(160, 64), 256, 0, stream>>>(wq, wk, wv, wo, Wqkv, Wo);
    qkv_gemm_kernel<<<dim3(12, 16), 512, 0, stream>>>(Xbf, Wqkv, Qb, Kb, Vt);
    rope_k_kernel<<<1024, 256, 0, stream>>>(Kb, pos, (const float4*)cst, (const float4*)snt);
    fa_kernel<<<512, 256, 0, stream>>>(Qb, Kb, Vt, Ob, pos, (const float4*)cst, (const float4*)snt);
    out_gemm_kernel<<<dim3(8, 32), 512, 0, stream>>>(Ob, Wo, out);
}

// Round 10
// 329.519 us; speedup vs baseline: 1.0336x; 1.0336x over previous
//
#include <hip/hip_runtime.h>
#include <cmath>

typedef unsigned short u16;
typedef float floatx4 __attribute__((ext_vector_type(4)));
typedef short short8 __attribute__((ext_vector_type(8)));
typedef short short4v __attribute__((ext_vector_type(4)));
typedef __bf16 bf16x8 __attribute__((ext_vector_type(8)));

#define GLOBAL_AS __attribute__((address_space(1)))
#define LDS_AS __attribute__((address_space(3)))

#define S_LEN 2048
#define D_MODEL 2048
#define NH 16
#define NKV 4
#define DHEAD 128
#define SM_SCALE 0.08838834764831843f
#define K2 (SM_SCALE * 1.4426950408889634f) /* SM_SCALE * log2(e) */

__device__ __forceinline__ u16 f2bf(float f) {
    unsigned int u = __builtin_bit_cast(unsigned int, f);
    u += 0x7fffu + ((u >> 16) & 1u);
    return (u16)(u >> 16);
}
__device__ __forceinline__ u16 f2bfr(float f) {
    unsigned int u = __builtin_bit_cast(unsigned int, f);
    return (u16)((u + 0x8000u) >> 16);
}
__device__ __forceinline__ float bf2f(u16 x) {
    unsigned int u = ((unsigned int)x) << 16;
    return __builtin_bit_cast(float, u);
}
__device__ __forceinline__ floatx4 zf4() {
    floatx4 z; z[0] = 0.f; z[1] = 0.f; z[2] = 0.f; z[3] = 0.f; return z;
}
__device__ __forceinline__ floatx4 mfma16(short8 a, short8 b, floatx4 c) {
    return __builtin_amdgcn_mfma_f32_16x16x32_bf16(
        __builtin_bit_cast(bf16x8, a), __builtin_bit_cast(bf16x8, b), c, 0, 0, 0);
}
__device__ __forceinline__ floatx4 mfma16k16(short4v a, short4v b, floatx4 c) {
    return __builtin_amdgcn_mfma_f32_16x16x16bf16_1k(a, b, c, 0, 0, 0);
}
__device__ __forceinline__ void async16(const u16* g, u16* l) {
    __builtin_amdgcn_global_load_lds((GLOBAL_AS void*)g, (LDS_AS void*)l, 16, 0, 0);
}

// ---------------- fused prologue: cast X, rope tables, weight transposes (one launch) ----------------
__global__ void prologue_kernel(const float4* __restrict__ Xin, ushort4* __restrict__ Xout,
                                float* __restrict__ cs_tab, float* __restrict__ sn_tab,
                                const float* __restrict__ wq, const float* __restrict__ wk,
                                const float* __restrict__ wv, const float* __restrict__ wo,
                                u16* __restrict__ Wqkv, u16* __restrict__ Wo) {
    __shared__ float tile[32][33];
    int bid = blockIdx.x;
    if (bid < 8192) {
        int i = bid * 256 + threadIdx.x;
        float4 v = Xin[i];
        ushort4 o;
        o.x = f2bf(v.x); o.y = f2bf(v.y); o.z = f2bf(v.z); o.w = f2bf(v.w);
        Xout[i] = o;
        return;
    }
    if (bid < 8704) {
        int idx = (bid - 8192) * 256 + threadIdx.x;  // 2048*64
        int p = idx >> 6, jj = idx & 63;
        double e = (double)(2 * jj) / 128.0;
        double invf = pow(10000.0, -e);
        float arg = (float)p * (float)invf;  // match reference's fp32 angle
        cs_tab[idx] = (float)cos((double)arg);
        sn_tab[idx] = (float)sin((double)arg);
        return;
    }
    int tb = bid - 8704;                 // 0..10239 = 160 x-chunks * 64 y-chunks
    int x = tb % 160, y = tb / 160;
    const float* in; u16* out; int C, bx;
    if (x < 64)      { in = wq; out = Wqkv;                     C = 2048; bx = x * 32; }
    else if (x < 80) { in = wk; out = Wqkv + (size_t)2048*2048; C = 512;  bx = (x - 64) * 32; }
    else if (x < 96) { in = wv; out = Wqkv + (size_t)2560*2048; C = 512;  bx = (x - 80) * 32; }
    else             { in = wo; out = Wo;                       C = 2048; bx = (x - 96) * 32; }
    const int R = 2048;
    int tx = threadIdx.x & 31, ty = threadIdx.x >> 5;
    int by = y * 32;
#pragma unroll
    for (int i = 0; i < 32; i += 8)
        tile[ty + i][tx] = in[(size_t)(by + ty + i) * C + bx + tx];
    __syncthreads();
#pragma unroll
    for (int i = 0; i < 32; i += 8)
        out[(size_t)(bx + ty + i) * R + by + tx] = f2bf(tile[tx][ty + i]);
}

// ---------------- apply RoPE in place on K only (Q rope is fused into fa) ----------------
__global__ void rope_k_kernel(u16* __restrict__ Kb, const int* __restrict__ pos,
                              const float4* __restrict__ cs_tab,
                              const float4* __restrict__ sn_tab) {
    int idx = blockIdx.x * 256 + threadIdx.x;  // 2*4*2048*16 = 262144
    int j4 = idx & 15;
    int s = (idx >> 4) & 2047;
    int r = idx >> 15;        // b*4 + hh
    int hh = r & 3, b = r >> 2;
    int p = pos[b * S_LEN + s];
    float4 cs = cs_tab[p * 16 + j4];
    float4 sn = sn_tab[p * 16 + j4];
    u16* base = Kb + (((size_t)(b * NKV + hh)) * S_LEN + s) * DHEAD + j4 * 4;
    ushort4 a = *(const ushort4*)(base);
    ushort4 c = *(const ushort4*)(base + 64);
    ushort4 oa, oc;
    float x1, x2;
    x1 = bf2f(a.x); x2 = bf2f(c.x); oa.x = f2bf(x1 * cs.x - x2 * sn.x); oc.x = f2bf(x2 * cs.x + x1 * sn.x);
    x1 = bf2f(a.y); x2 = bf2f(c.y); oa.y = f2bf(x1 * cs.y - x2 * sn.y); oc.y = f2bf(x2 * cs.y + x1 * sn.y);
    x1 = bf2f(a.z); x2 = bf2f(c.z); oa.z = f2bf(x1 * cs.z - x2 * sn.z); oc.z = f2bf(x2 * cs.z + x1 * sn.z);
    x1 = bf2f(a.w); x2 = bf2f(c.w); oa.w = f2bf(x1 * cs.w - x2 * sn.w); oc.w = f2bf(x2 * cs.w + x1 * sn.w);
    *(ushort4*)(base) = oa;
    *(ushort4*)(base + 64) = oc;
}

// ---------------- deep-pipelined GEMM mainloop (BK=64, 8 waves 2Mx4N, BN=256) ----------------
// Per K-tile: P0 stages the ENTIRE next tile -> buf[nxt]; vmcnt(TLOADS) retires
// exactly the current tile's loads (issued one full tile ago, covered by 2-5
// MFMA phases), keeps the next tile's in flight (counted, never 0 in-loop);
// s_barrier makes tile kt visible to ALL waves (r8's race fix: never ds_read
// before this barrier).  Then MFMA phases: M_REP==8 -> 4 quadrant phases of
// 16 MFMA; M_REP==4 -> 2 m-half phases of 16 MFMA (8-per-phase was below the
// template's granularity minimum).  End-of-tile barrier protects buf[cur]
// from the next tile's stages.  XOR-chunk swizzle: conflict-free b128 reads.
template <int M_REP>
__device__ __forceinline__ void gemm_ph(const u16* __restrict__ A,
                                        const u16* __restrict__ Bt, int K,
                                        u16* ldsA, u16* ldsB,
                                        floatx4 acc[M_REP][4],
                                        int m0, int n0) {
    constexpr int BM = M_REP * 32;
    constexpr int ALOADS = BM / 64;      // A gloads/thread per tile (4 qkv, 2 out)
    const int t = threadIdx.x;
    const int lane = t & 63, wave = t >> 6;
    const int wr = wave >> 2, wc = wave & 3;
    const int lr = lane & 15, q = lane >> 4;
    const int swz = lr & 7;

#pragma unroll
    for (int r = 0; r < M_REP; ++r)
#pragma unroll
        for (int c = 0; c < 4; ++c) acc[r][c] = zf4();

    auto stageT = [&](int kt, int bs) {  // full tile: A then B
#pragma unroll
        for (int i = 0; i < ALOADS; ++i) {
            int ci = i * 512 + t;
            int grow = ci >> 3;
            int kc = ((ci & 7) ^ (grow & 7)) << 3;
            async16(A + (size_t)(m0 + grow) * K + kt * 64 + kc,
                    ldsA + bs * (BM * 64) + (i * 512 + wave * 64) * 8);
        }
#pragma unroll
        for (int i = 0; i < 4; ++i) {
            int ci = i * 512 + t;
            int grow = ci >> 3;
            int kc = ((ci & 7) ^ (grow & 7)) << 3;
            async16(Bt + (size_t)(n0 + grow) * K + kt * 64 + kc,
                    ldsB + bs * (256 * 64) + (i * 512 + wave * 64) * 8);
        }
    };

    const int NT = K / 64;
    stageT(0, 0);

    for (int kt = 0; kt < NT; ++kt) {
        const int cur = kt & 1, nxt = cur ^ 1;
        const int kn = (kt + 1 < NT) ? kt + 1 : 0;  // dummy re-stage on last tile
        const u16* la = ldsA + cur * (BM * 64);
        const u16* lb = ldsB + cur * (256 * 64);

        stageT(kn, nxt);
        if constexpr (M_REP == 8) asm volatile("s_waitcnt vmcnt(8)" ::: "memory");
        else                      asm volatile("s_waitcnt vmcnt(6)" ::: "memory");
        __builtin_amdgcn_s_barrier();  // tile kt visible to all waves

        if constexpr (M_REP == 8) {
            short8 af[4][2], bf[4][2];
            // ---- P0: quadrant (0,0) ----
#pragma unroll
            for (int nf = 0; nf < 2; ++nf)
#pragma unroll
                for (int ks = 0; ks < 2; ++ks)
                    bf[nf][ks] = *(const short8*)(lb + (wc * 64 + nf * 16 + lr) * 64 +
                                                  (((ks * 4 + q) ^ swz) << 3));
#pragma unroll
            for (int mf = 0; mf < 4; ++mf)
#pragma unroll
                for (int ks = 0; ks < 2; ++ks)
                    af[mf][ks] = *(const short8*)(la + (wr * 128 + mf * 16 + lr) * 64 +
                                                  (((ks * 4 + q) ^ swz) << 3));
            __builtin_amdgcn_s_barrier();
            __builtin_amdgcn_s_setprio(1);
#pragma unroll
            for (int mf = 0; mf < 4; ++mf)
#pragma unroll
                for (int nf = 0; nf < 2; ++nf)
#pragma unroll
                    for (int ks = 0; ks < 2; ++ks)
                        acc[mf][nf] = mfma16(af[mf][ks], bf[nf][ks], acc[mf][nf]);
            __builtin_amdgcn_s_setprio(0);
            __builtin_amdgcn_s_barrier();
            // ---- P1: quadrant (0,1) ----
#pragma unroll
            for (int nf = 0; nf < 2; ++nf)
#pragma unroll
                for (int ks = 0; ks < 2; ++ks)
                    bf[2 + nf][ks] = *(const short8*)(lb + (wc * 64 + (2 + nf) * 16 + lr) * 64 +
                                                      (((ks * 4 + q) ^ swz) << 3));
            __builtin_amdgcn_s_barrier();
            __builtin_amdgcn_s_setprio(1);
#pragma unroll
            for (int mf = 0; mf < 4; ++mf)
#pragma unroll
                for (int nf = 2; nf < 4; ++nf)
#pragma unroll
                    for (int ks = 0; ks < 2; ++ks)
                        acc[mf][nf] = mfma16(af[mf][ks], bf[nf][ks], acc[mf][nf]);
            __builtin_amdgcn_s_setprio(0);
            __builtin_amdgcn_s_barrier();
            // ---- P2: quadrant (1,0) ----
#pragma unroll
            for (int mf = 0; mf < 4; ++mf)
#pragma unroll
                for (int ks = 0; ks < 2; ++ks)
                    af[mf][ks] = *(const short8*)(la + (wr * 128 + (4 + mf) * 16 + lr) * 64 +
                                                  (((ks * 4 + q) ^ swz) << 3));
            __builtin_amdgcn_s_barrier();
            __builtin_amdgcn_s_setprio(1);
#pragma unroll
            for (int mf = 0; mf < 4; ++mf)
#pragma unroll
                for (int nf = 0; nf < 2; ++nf)
#pragma unroll
                    for (int ks = 0; ks < 2; ++ks)
                        acc[4 + mf][nf] = mfma16(af[mf][ks], bf[nf][ks], acc[4 + mf][nf]);
            __builtin_amdgcn_s_setprio(0);
            __builtin_amdgcn_s_barrier();
            // ---- P3: quadrant (1,1) ----
            __builtin_amdgcn_s_setprio(1);
#pragma unroll
            for (int mf = 0; mf < 4; ++mf)
#pragma unroll
                for (int nf = 2; nf < 4; ++nf)
#pragma unroll
                    for (int ks = 0; ks < 2; ++ks)
                        acc[4 + mf][nf] = mfma16(af[mf][ks], bf[nf][ks], acc[4 + mf][nf]);
            __builtin_amdgcn_s_setprio(0);
            __builtin_amdgcn_s_barrier();  // end-of-tile: buf[cur] reads done
        } else {
            short8 af[2][2], bf[4][2];
            // ---- P0: m-half 0, all n (16 MFMA) ----
#pragma unroll
            for (int nf = 0; nf < 4; ++nf)
#pragma unroll
                for (int ks = 0; ks < 2; ++ks)
                    bf[nf][ks] = *(const short8*)(lb + (wc * 64 + nf * 16 + lr) * 64 +
                                                  (((ks * 4 + q) ^ swz) << 3));
#pragma unroll
            for (int mf = 0; mf < 2; ++mf)
#pragma unroll
                for (int ks = 0; ks < 2; ++ks)
                    af[mf][ks] = *(const short8*)(la + (wr * 64 + mf * 16 + lr) * 64 +
                                                  (((ks * 4 + q) ^ swz) << 3));
            __builtin_amdgcn_s_barrier();
            __builtin_amdgcn_s_setprio(1);
#pragma unroll
            for (int mf = 0; mf < 2; ++mf)
#pragma unroll
                for (int nf = 0; nf < 4; ++nf)
#pragma unroll
                    for (int ks = 0; ks < 2; ++ks)
                        acc[mf][nf] = mfma16(af[mf][ks], bf[nf][ks], acc[mf][nf]);
            __builtin_amdgcn_s_setprio(0);
            __builtin_amdgcn_s_barrier();
            // ---- P1: m-half 1, all n (16 MFMA) ----
#pragma unroll
            for (int mf = 0; mf < 2; ++mf)
#pragma unroll
                for (int ks = 0; ks < 2; ++ks)
                    af[mf][ks] = *(const short8*)(la + (wr * 64 + (2 + mf) * 16 + lr) * 64 +
                                                  (((ks * 4 + q) ^ swz) << 3));
            __builtin_amdgcn_s_barrier();
            __builtin_amdgcn_s_setprio(1);
#pragma unroll
            for (int mf = 0; mf < 2; ++mf)
#pragma unroll
                for (int nf = 0; nf < 4; ++nf)
#pragma unroll
                    for (int ks = 0; ks < 2; ++ks)
                        acc[2 + mf][nf] = mfma16(af[mf][ks], bf[nf][ks], acc[2 + mf][nf]);
            __builtin_amdgcn_s_setprio(0);
            __builtin_amdgcn_s_barrier();  // end-of-tile
        }
    }
    asm volatile("s_waitcnt vmcnt(0)" ::: "memory");  // drain dummy loads
}

// ---------------- QKV GEMM (256x256, XCD-grouped): scatter epilogue ----------------
// Grid 192 1-D.  xcd = bid&7 gets y in {2*xcd, 2*xcd+1} x all 12 x -> the 12
// blocks sharing an A-panel co-reside on ONE XCD's L2 (T1 mechanism: A was
// being fetched into up to 8 non-coherent L2s -> FETCH 80 MB vs 29 ideal).
__global__ __launch_bounds__(512, 1) void qkv_gemm_kernel(const u16* __restrict__ A,
                                                          const u16* __restrict__ Bt,
                                                          u16* __restrict__ Qb,
                                                          u16* __restrict__ Kb,
                                                          u16* __restrict__ Vt) {
    __shared__ u16 ldsA[2 * 256 * 64];
    __shared__ u16 ldsB[2 * 256 * 64];
    const int xcd = blockIdx.x & 7, slot = blockIdx.x >> 3;  // slot 0..23
    const int by = 2 * xcd + (slot >= 12), bx = slot % 12;
    const int m0 = by * 256, n0 = bx * 256;

    floatx4 acc[8][4];
    gemm_ph<8>(A, Bt, D_MODEL, ldsA, ldsB, acc, m0, n0);

    const int t = threadIdx.x, lane = t & 63, wave = t >> 6;
    const int wr = wave >> 2, wc = wave & 3, lr = lane & 15, q = lane >> 4;
    const int em0 = m0 + wr * 128, en0 = n0 + wc * 64;
#pragma unroll
    for (int r = 0; r < 8; ++r)
#pragma unroll
        for (int c = 0; c < 4; ++c) {
            int gc = en0 + c * 16 + lr;
#pragma unroll
            for (int rr = 0; rr < 4; ++rr) {
                int grow = em0 + r * 16 + q * 4 + rr;  // token
                int bb = grow >> 11, s = grow & 2047;
                u16 bv = f2bf(acc[r][c][rr]);
                int d = gc & 127;
                if (gc < 2048) {
                    int hh = gc >> 7;
                    Qb[(((size_t)(bb * NH + hh)) * S_LEN + s) * DHEAD + d] = bv;
                } else if (gc < 2560) {
                    int hh = (gc - 2048) >> 7;
                    Kb[(((size_t)(bb * NKV + hh)) * S_LEN + s) * DHEAD + d] = bv;
                } else {
                    int hh = (gc - 2560) >> 7;
                    int s2 = s ^ ((d & 8) >> 1);  // V half-spread (fa's b64 V reads)
                    Vt[(((size_t)(bb * NKV + hh)) * DHEAD + d) * S_LEN + s2] = bv;
                }
            }
        }
}

// ---------------- out GEMM (128x256, XCD-grouped; grid 256 = 1 block/CU) ----------------
__global__ __launch_bounds__(512, 1) void out_gemm_kernel(const u16* __restrict__ A,
                                                          const u16* __restrict__ Bt,
                                                          float* __restrict__ out) {
    __shared__ u16 ldsA[2 * 128 * 64];
    __shared__ u16 ldsB[2 * 256 * 64];
    const int xcd = blockIdx.x & 7, slot = blockIdx.x >> 3;  // slot 0..31
    const int by = 4 * xcd + (slot >> 3), bx = slot & 7;
    const int m0 = by * 128, n0 = bx * 256;

    floatx4 acc[4][4];
    gemm_ph<4>(A, Bt, D_MODEL, ldsA, ldsB, acc, m0, n0);

    const int t = threadIdx.x, lane = t & 63, wave = t >> 6;
    const int wr = wave >> 2, wc = wave & 3, lr = lane & 15, q = lane >> 4;
    const int em0 = m0 + wr * 64, en0 = n0 + wc * 64;
#pragma unroll
    for (int r = 0; r < 4; ++r)
#pragma unroll
        for (int c = 0; c < 4; ++c) {
            int gc = en0 + c * 16 + lr;
#pragma unroll
            for (int rr = 0; rr < 4; ++rr) {
                int grow = em0 + r * 16 + q * 4 + rr;
                out[(size_t)grow * D_MODEL + gc] = acc[r][c][rr];
            }
        }
}

// ---------------- flash attention (r3 version, best measured: 85.2 us) ----------------
__global__ __launch_bounds__(256, 2) void fa_kernel(const u16* __restrict__ Qb,
                                                    const u16* __restrict__ Kb,
                                                    const u16* __restrict__ Vt,
                                                    u16* __restrict__ Ob,
                                                    const int* __restrict__ pos,
                                                    const float4* __restrict__ cs_tab,
                                                    const float4* __restrict__ sn_tab) {
    __shared__ u16 ldsK[2][64 * 128];
    __shared__ u16 ldsV[2][128 * 64];

    const int t = threadIdx.x, lane = t & 63, wave = t >> 6;
    const int lr = lane & 15, q = lane >> 4;
    const int swz = lr & 7;

    const int bid = blockIdx.x;
    const int bh = bid >> 4, p = bid & 15;
    const int qt0 = p, qt1 = 31 - p;
    const int b = bh >> 4, h = bh & 15;
    const int kvh = h >> 2;

    const u16* Kp = Kb + (size_t)(b * NKV + kvh) * S_LEN * DHEAD;
    const u16* Vp = Vt + (size_t)(b * NKV + kvh) * DHEAD * S_LEN;

    short8 qf0[4], qf1[4];
    auto load_rope_q = [&](int qt, short8 (&qf)[4]) {
        const u16* Qp = Qb + ((size_t)((b * NH + h) * S_LEN) + qt * 64 + wave * 16) * DHEAD;
#pragma unroll
        for (int kk = 0; kk < 4; ++kk)
            qf[kk] = *(const short8*)(Qp + (size_t)lr * DHEAD + kk * 32 + q * 8);
        const int srow = qt * 64 + wave * 16 + lr;
        const int pp = pos[b * S_LEN + srow];
#pragma unroll
        for (int kk = 0; kk < 2; ++kk)
#pragma unroll
            for (int h4 = 0; h4 < 2; ++h4) {
                float4 cs = cs_tab[pp * 16 + kk * 8 + q * 2 + h4];
                float4 sn = sn_tab[pp * 16 + kk * 8 + q * 2 + h4];
#pragma unroll
                for (int e = 0; e < 4; ++e) {
                    float cc = (&cs.x)[e], ss = (&sn.x)[e];
                    int ei = h4 * 4 + e;
                    float x1 = bf2f((u16)qf[kk][ei]);
                    float x2 = bf2f((u16)qf[kk + 2][ei]);
                    qf[kk][ei]     = (short)f2bf(x1 * cc - x2 * ss);
                    qf[kk + 2][ei] = (short)f2bf(x2 * cc + x1 * ss);
                }
            }
    };
    load_rope_q(qt0, qf0);
    load_rope_q(qt1, qf1);

    auto stage = [&](int kt, int bs) {
#pragma unroll
        for (int i = 0; i < 4; ++i) {
            int ci = i * 256 + t;
            int krow = ci >> 4, kc = ((ci & 15) ^ ((ci >> 4) & 7)) << 3;
            async16(Kp + (size_t)(kt * 64 + krow) * DHEAD + kc,
                    &ldsK[bs][(i * 256 + wave * 64) * 8]);
            int dh = ci >> 3, vc = ((ci & 7) ^ ((ci >> 3) & 7)) << 3;
            async16(Vp + (size_t)dh * S_LEN + kt * 64 + vc,
                    &ldsV[bs][(i * 256 + wave * 64) * 8]);
        }
    };

    floatx4 accO[8];
    float m_i, l_i;

    auto do_tile = [&](int kt, int qt_c, const short8 (&qfc)[4], int bs) {
        floatx4 sc[4];
        __builtin_amdgcn_s_setprio(1);
#pragma unroll
        for (int c = 0; c < 4; ++c) {
            sc[c] = zf4();
#pragma unroll
            for (int kk = 0; kk < 4; ++kk) {
                short8 kfr = *(const short8*)(&ldsK[bs][(c * 16 + lr) * DHEAD +
                                              (((kk * 4 + q) ^ swz) << 3)]);
                sc[c] = mfma16(kfr, qfc[kk], sc[c]);
            }
        }
        __builtin_amdgcn_s_setprio(0);

        if (kt == qt_c) {
            const int qrow = wave * 16 + lr;
#pragma unroll
            for (int c = 0; c < 4; ++c)
#pragma unroll
                for (int rr = 0; rr < 4; ++rr)
                    if (c * 16 + q * 4 + rr > qrow) sc[c][rr] = -3e38f;
        }

        float mx = -3e38f;
#pragma unroll
        for (int c = 0; c < 4; ++c)
#pragma unroll
            for (int rr = 0; rr < 4; ++rr) mx = fmaxf(mx, sc[c][rr]);
        mx = fmaxf(mx, __shfl_xor(mx, 16));
        mx = fmaxf(mx, __shfl_xor(mx, 32));
        float mnew = fmaxf(m_i, mx);
        float mk = mnew * K2;
        bool anyup = __any(mnew > m_i);
        float rs = 0.f;
#pragma unroll
        for (int c = 0; c < 4; ++c)
#pragma unroll
            for (int rr = 0; rr < 4; ++rr) {
                float pe = __builtin_amdgcn_exp2f(fmaf(sc[c][rr], K2, -mk));
                sc[c][rr] = pe;
                rs += pe;
            }
        rs += __shfl_xor(rs, 16);
        rs += __shfl_xor(rs, 32);
        if (anyup) {
            float alpha = __builtin_amdgcn_exp2f(fmaf(m_i, K2, -mk));
            l_i = l_i * alpha + rs;
#pragma unroll
            for (int d = 0; d < 8; ++d) accO[d] *= alpha;
        } else {
            l_i += rs;
        }
        m_i = mnew;

        short4v pb[4];
#pragma unroll
        for (int c = 0; c < 4; ++c) {
            pb[c][0] = (short)f2bfr(sc[c][0]);
            pb[c][1] = (short)f2bfr(sc[c][1]);
            pb[c][2] = (short)f2bfr(sc[c][2]);
            pb[c][3] = (short)f2bfr(sc[c][3]);
        }

        __builtin_amdgcn_s_setprio(1);
#pragma unroll
        for (int ks = 0; ks < 4; ++ks)
#pragma unroll
            for (int d = 0; d < 8; ++d) {
                short4v vf = *(const short4v*)(&ldsV[bs][(d * 16 + lr) * 64 +
                                               (((ks * 2 + (q >> 1)) ^ swz) << 3) +
                                               (((q ^ (lr >> 3)) & 1) << 2)]);
                accO[d] = mfma16k16(vf, pb[ks], accO[d]);
            }
        __builtin_amdgcn_s_setprio(0);
    };

    auto epilogue = [&](int qt_c) {
        const int tok = qt_c * 64 + wave * 16 + lr;
        const float inv = 1.0f / l_i;
        u16* orow = Ob + ((size_t)(b * S_LEN + tok)) * (NH * DHEAD) + h * DHEAD + q * 4;
#pragma unroll
        for (int d = 0; d < 8; ++d) {
            ushort4 o;
            o.x = f2bf(accO[d][0] * inv);
            o.y = f2bf(accO[d][1] * inv);
            o.z = f2bf(accO[d][2] * inv);
            o.w = f2bf(accO[d][3] * inv);
            *(ushort4*)(orow + d * 16) = o;
        }
    };

#pragma unroll
    for (int d = 0; d < 8; ++d) accO[d] = zf4();
    m_i = -3e38f; l_i = 0.f;

    int cur = 0;
    stage(0, 0);
    __syncthreads();

    for (int kt = 0; kt <= qt0; ++kt) {
        int nxt = cur ^ 1;
        int nk = (kt < qt0) ? kt + 1 : 0;  // last tile prefetches seg-1 kt=0
        stage(nk, nxt);
        do_tile(kt, qt0, qf0, cur);
        __syncthreads();
        cur = nxt;
    }
    epilogue(qt0);
#pragma unroll
    for (int d = 0; d < 8; ++d) accO[d] = zf4();
    m_i = -3e38f; l_i = 0.f;

    for (int kt = 0; kt <= qt1; ++kt) {
        int nxt = cur ^ 1;
        if (kt < qt1) stage(kt + 1, nxt);
        do_tile(kt, qt1, qf1, cur);
        __syncthreads();
        cur = nxt;
    }
    epilogue(qt1);
}

extern "C" void kernel_launch(void* const* d_in, const int* in_sizes, int n_in,
                              void* d_out, int out_size, void* d_ws, size_t ws_size,
                              hipStream_t stream) {
    const float* X  = (const float*)d_in[0];
    const int* pos  = (const int*)d_in[1];
    const float* wq = (const float*)d_in[2];
    const float* wk = (const float*)d_in[3];
    const float* wv = (const float*)d_in[4];
    const float* wo = (const float*)d_in[5];
    float* out = (float*)d_out;

    char* w = (char*)d_ws;
    u16* Xbf    = (u16*)(w);                    // 4096*2048*2      = 16777216
    u16* Wqkv   = (u16*)(w + 16777216);         // 3072*2048*2      = 12582912
    u16* Wo     = (u16*)(w + 29360128);         // 2048*2048*2      =  8388608
    u16* Qb     = (u16*)(w + 37748736);         // 2*16*2048*128*2  = 16777216
    u16* Kb     = (u16*)(w + 54525952);         // 2*4*2048*128*2   =  4194304
    u16* Vt     = (u16*)(w + 58720256);         //                  =  4194304
    u16* Ob     = (u16*)(w + 62914560);         // 4096*2048*2      = 16777216
    float* cst  = (float*)(w + 79691776);       // 2048*64*4        =   524288
    float* snt  = (float*)(w + 80216064);       //                  =   524288

    prologue_kernel<<<18944, 256, 0, stream>>>((const float4*)X, (ushort4*)Xbf, cst, snt,
                                               wq, wk, wv, wo, Wqkv, Wo);
    qkv_gemm_kernel<<<192, 512, 0, stream>>>(Xbf, Wqkv, Qb, Kb, Vt);
    rope_k_kernel<<<1024, 256, 0, stream>>>(Kb, pos, (const float4*)cst, (const float4*)snt);
    fa_kernel<<<512, 256, 0, stream>>>(Qb, Kb, Vt, Ob, pos, (const float4*)cst, (const float4*)snt);
    out_gemm_kernel<<<256, 512, 0, stream>>>(Ob, Wo, out);
}

// Round 11
// 297.947 us; speedup vs baseline: 1.1431x; 1.1060x over previous
//
#include <hip/hip_runtime.h>
#include <cmath>

typedef unsigned short u16;
typedef float floatx4 __attribute__((ext_vector_type(4)));
typedef short short8 __attribute__((ext_vector_type(8)));
typedef short short4v __attribute__((ext_vector_type(4)));
typedef __bf16 bf16x8 __attribute__((ext_vector_type(8)));

#define GLOBAL_AS __attribute__((address_space(1)))
#define LDS_AS __attribute__((address_space(3)))

#define S_LEN 2048
#define D_MODEL 2048
#define NH 16
#define NKV 4
#define DHEAD 128
#define SM_SCALE 0.08838834764831843f
#define K2 (SM_SCALE * 1.4426950408889634f) /* SM_SCALE * log2(e) */

__device__ __forceinline__ u16 f2bf(float f) {
    unsigned int u = __builtin_bit_cast(unsigned int, f);
    u += 0x7fffu + ((u >> 16) & 1u);
    return (u16)(u >> 16);
}
__device__ __forceinline__ u16 f2bfr(float f) {
    unsigned int u = __builtin_bit_cast(unsigned int, f);
    return (u16)((u + 0x8000u) >> 16);
}
__device__ __forceinline__ float bf2f(u16 x) {
    unsigned int u = ((unsigned int)x) << 16;
    return __builtin_bit_cast(float, u);
}
__device__ __forceinline__ floatx4 zf4() {
    floatx4 z; z[0] = 0.f; z[1] = 0.f; z[2] = 0.f; z[3] = 0.f; return z;
}
__device__ __forceinline__ floatx4 mfma16(short8 a, short8 b, floatx4 c) {
    return __builtin_amdgcn_mfma_f32_16x16x32_bf16(
        __builtin_bit_cast(bf16x8, a), __builtin_bit_cast(bf16x8, b), c, 0, 0, 0);
}
__device__ __forceinline__ floatx4 mfma16k16(short4v a, short4v b, floatx4 c) {
    return __builtin_amdgcn_mfma_f32_16x16x16bf16_1k(a, b, c, 0, 0, 0);
}
__device__ __forceinline__ void async16(const u16* g, u16* l) {
    __builtin_amdgcn_global_load_lds((GLOBAL_AS void*)g, (LDS_AS void*)l, 16, 0, 0);
}

// ---------------- fused prologue: cast X, rope tables, weight transposes (one launch) ----------------
__global__ void prologue_kernel(const float4* __restrict__ Xin, ushort4* __restrict__ Xout,
                                float* __restrict__ cs_tab, float* __restrict__ sn_tab,
                                const float* __restrict__ wq, const float* __restrict__ wk,
                                const float* __restrict__ wv, const float* __restrict__ wo,
                                u16* __restrict__ Wqkv, u16* __restrict__ Wo) {
    __shared__ float tile[32][33];
    int bid = blockIdx.x;
    if (bid < 8192) {
        int i = bid * 256 + threadIdx.x;
        float4 v = Xin[i];
        ushort4 o;
        o.x = f2bf(v.x); o.y = f2bf(v.y); o.z = f2bf(v.z); o.w = f2bf(v.w);
        Xout[i] = o;
        return;
    }
    if (bid < 8704) {
        int idx = (bid - 8192) * 256 + threadIdx.x;  // 2048*64
        int p = idx >> 6, jj = idx & 63;
        double e = (double)(2 * jj) / 128.0;
        double invf = pow(10000.0, -e);
        float arg = (float)p * (float)invf;  // match reference's fp32 angle
        cs_tab[idx] = (float)cos((double)arg);
        sn_tab[idx] = (float)sin((double)arg);
        return;
    }
    int tb = bid - 8704;                 // 0..10239 = 160 x-chunks * 64 y-chunks
    int x = tb % 160, y = tb / 160;
    const float* in; u16* out; int C, bx;
    if (x < 64)      { in = wq; out = Wqkv;                     C = 2048; bx = x * 32; }
    else if (x < 80) { in = wk; out = Wqkv + (size_t)2048*2048; C = 512;  bx = (x - 64) * 32; }
    else if (x < 96) { in = wv; out = Wqkv + (size_t)2560*2048; C = 512;  bx = (x - 80) * 32; }
    else             { in = wo; out = Wo;                       C = 2048; bx = (x - 96) * 32; }
    const int R = 2048;
    int tx = threadIdx.x & 31, ty = threadIdx.x >> 5;
    int by = y * 32;
#pragma unroll
    for (int i = 0; i < 32; i += 8)
        tile[ty + i][tx] = in[(size_t)(by + ty + i) * C + bx + tx];
    __syncthreads();
#pragma unroll
    for (int i = 0; i < 32; i += 8)
        out[(size_t)(bx + ty + i) * R + by + tx] = f2bf(tile[tx][ty + i]);
}

// ---------------- apply RoPE in place on K only (Q rope is fused into fa) ----------------
__global__ void rope_k_kernel(u16* __restrict__ Kb, const int* __restrict__ pos,
                              const float4* __restrict__ cs_tab,
                              const float4* __restrict__ sn_tab) {
    int idx = blockIdx.x * 256 + threadIdx.x;  // 2*4*2048*16 = 262144
    int j4 = idx & 15;
    int s = (idx >> 4) & 2047;
    int r = idx >> 15;        // b*4 + hh
    int hh = r & 3, b = r >> 2;
    int p = pos[b * S_LEN + s];
    float4 cs = cs_tab[p * 16 + j4];
    float4 sn = sn_tab[p * 16 + j4];
    u16* base = Kb + (((size_t)(b * NKV + hh)) * S_LEN + s) * DHEAD + j4 * 4;
    ushort4 a = *(const ushort4*)(base);
    ushort4 c = *(const ushort4*)(base + 64);
    ushort4 oa, oc;
    float x1, x2;
    x1 = bf2f(a.x); x2 = bf2f(c.x); oa.x = f2bf(x1 * cs.x - x2 * sn.x); oc.x = f2bf(x2 * cs.x + x1 * sn.x);
    x1 = bf2f(a.y); x2 = bf2f(c.y); oa.y = f2bf(x1 * cs.y - x2 * sn.y); oc.y = f2bf(x2 * cs.y + x1 * sn.y);
    x1 = bf2f(a.z); x2 = bf2f(c.z); oa.z = f2bf(x1 * cs.z - x2 * sn.z); oc.z = f2bf(x2 * cs.z + x1 * sn.z);
    x1 = bf2f(a.w); x2 = bf2f(c.w); oa.w = f2bf(x1 * cs.w - x2 * sn.w); oc.w = f2bf(x2 * cs.w + x1 * sn.w);
    *(ushort4*)(base) = oa;
    *(ushort4*)(base + 64) = oc;
}

// ---------------- shared GEMM mainloop: A[M][K] bf16, Bt[N][K] bf16, 128x128 tile ----------------
// r3-proven structure (best measured config): BK=64, 4 waves 2x2, 32 KB LDS,
// ~4 blocks/CU co-resident -> implicit inter-block overlap (one block's staging
// hides under another's MFMA, m114 mechanism).  This beat both 8-wave 256^2
// ports (r7 coarse, r9/r10 phased): at K=2048 and this LDS-read ratio,
// co-residency > in-block pipelining.  XOR-chunk swizzle: slot c holds chunk
// c^(row&7) -> conflict-free ds_read_b128 (SQ_LDS_BANK_CONFLICT == 0, r10).
__device__ __forceinline__ void gemm_mainloop(const u16* __restrict__ A,
                                              const u16* __restrict__ Bt,
                                              int K, u16* ldsA, u16* ldsB,
                                              floatx4 acc[4][4], int m0, int n0) {
    const int t = threadIdx.x;
    const int lane = t & 63, wave = t >> 6;
    const int wr = wave >> 1, wc = wave & 1;
    const int lr = lane & 15, q = lane >> 4;
    const int swz = lr & 7;

#pragma unroll
    for (int r = 0; r < 4; ++r)
#pragma unroll
        for (int c = 0; c < 4; ++c) acc[r][c] = zf4();

    for (int k0 = 0; k0 < K; k0 += 64) {
#pragma unroll
        for (int i = 0; i < 4; ++i) {
            int ci = i * 256 + t;
            int row = ci >> 3;
            int kc = ((ci & 7) ^ (row & 7)) << 3;
            async16(A + (size_t)(m0 + row) * K + k0 + kc, ldsA + (i * 256 + wave * 64) * 8);
            async16(Bt + (size_t)(n0 + row) * K + k0 + kc, ldsB + (i * 256 + wave * 64) * 8);
        }
        __syncthreads();
#pragma unroll
        for (int ks = 0; ks < 2; ++ks) {
            short8 af[4], bfr[4];
#pragma unroll
            for (int r = 0; r < 4; ++r)
                af[r] = *(const short8*)(ldsA + (wr * 64 + r * 16 + lr) * 64 +
                                         (((ks * 4 + q) ^ swz) << 3));
#pragma unroll
            for (int c = 0; c < 4; ++c)
                bfr[c] = *(const short8*)(ldsB + (wc * 64 + c * 16 + lr) * 64 +
                                          (((ks * 4 + q) ^ swz) << 3));
#pragma unroll
            for (int r = 0; r < 4; ++r)
#pragma unroll
                for (int c = 0; c < 4; ++c)
                    acc[r][c] = mfma16(af[r], bfr[c], acc[r][c]);
        }
        __syncthreads();
    }
}

// ---------------- QKV GEMM (128x128, XCD-grouped 1-D grid 768) ----------------
// xcd = bid&7; slot = bid>>3 (0..95): y = 4*xcd + slot/24 (A-panel), x = slot%24.
// The 24 blocks sharing an A-panel co-reside on one XCD's L2 (T1; r10 showed
// FETCH 80->59 MB from this mechanism on the 256^2 version).
__global__ void qkv_gemm_kernel(const u16* __restrict__ A, const u16* __restrict__ Bt,
                                u16* __restrict__ Qb, u16* __restrict__ Kb,
                                u16* __restrict__ Vt) {
    __shared__ u16 ldsA[128 * 64];
    __shared__ u16 ldsB[128 * 64];
    const int xcd = blockIdx.x & 7, slot = blockIdx.x >> 3;
    const int by = 4 * xcd + slot / 24, bx = slot % 24;
    const int m0 = by * 128, n0 = bx * 128;

    floatx4 acc[4][4];
    gemm_mainloop(A, Bt, D_MODEL, ldsA, ldsB, acc, m0, n0);

    const int t = threadIdx.x, lane = t & 63, wave = t >> 6;
    const int wr = wave >> 1, wc = wave & 1, lr = lane & 15, q = lane >> 4;
    const int em0 = m0 + wr * 64, en0 = n0 + wc * 64;
#pragma unroll
    for (int r = 0; r < 4; ++r)
#pragma unroll
        for (int c = 0; c < 4; ++c) {
            int gc = en0 + c * 16 + lr;
#pragma unroll
            for (int rr = 0; rr < 4; ++rr) {
                int grow = em0 + r * 16 + q * 4 + rr;  // token
                int bb = grow >> 11, s = grow & 2047;
                u16 bv = f2bf(acc[r][c][rr]);
                int d = gc & 127;
                if (gc < 2048) {
                    int hh = gc >> 7;
                    Qb[(((size_t)(bb * NH + hh)) * S_LEN + s) * DHEAD + d] = bv;
                } else if (gc < 2560) {
                    int hh = (gc - 2048) >> 7;
                    Kb[(((size_t)(bb * NKV + hh)) * S_LEN + s) * DHEAD + d] = bv;
                } else {
                    int hh = (gc - 2560) >> 7;
                    int s2 = s ^ ((d & 8) >> 1);  // V half-spread (fa's b64 V reads)
                    Vt[(((size_t)(bb * NKV + hh)) * DHEAD + d) * S_LEN + s2] = bv;
                }
            }
        }
}

// ---------------- out GEMM (128x128, XCD-grouped 1-D grid 512) ----------------
// xcd = bid&7; slot = bid>>3 (0..63): y = 4*xcd + slot/16, x = slot%16.
__global__ void out_gemm_kernel(const u16* __restrict__ A, const u16* __restrict__ Bt,
                                float* __restrict__ out) {
    __shared__ u16 ldsA[128 * 64];
    __shared__ u16 ldsB[128 * 64];
    const int xcd = blockIdx.x & 7, slot = blockIdx.x >> 3;
    const int by = 4 * xcd + slot / 16, bx = slot % 16;
    const int m0 = by * 128, n0 = bx * 128;

    floatx4 acc[4][4];
    gemm_mainloop(A, Bt, D_MODEL, ldsA, ldsB, acc, m0, n0);

    const int t = threadIdx.x, lane = t & 63, wave = t >> 6;
    const int wr = wave >> 1, wc = wave & 1, lr = lane & 15, q = lane >> 4;
    const int em0 = m0 + wr * 64, en0 = n0 + wc * 64;
#pragma unroll
    for (int r = 0; r < 4; ++r)
#pragma unroll
        for (int c = 0; c < 4; ++c) {
            int gc = en0 + c * 16 + lr;
#pragma unroll
            for (int rr = 0; rr < 4; ++rr) {
                int grow = em0 + r * 16 + q * 4 + rr;
                out[(size_t)grow * D_MODEL + gc] = acc[r][c][rr];
            }
        }
}

// ---------------- flash attention (r3 version, best measured: 85.2 us) ----------------
__global__ __launch_bounds__(256, 2) void fa_kernel(const u16* __restrict__ Qb,
                                                    const u16* __restrict__ Kb,
                                                    const u16* __restrict__ Vt,
                                                    u16* __restrict__ Ob,
                                                    const int* __restrict__ pos,
                                                    const float4* __restrict__ cs_tab,
                                                    const float4* __restrict__ sn_tab) {
    __shared__ u16 ldsK[2][64 * 128];
    __shared__ u16 ldsV[2][128 * 64];

    const int t = threadIdx.x, lane = t & 63, wave = t >> 6;
    const int lr = lane & 15, q = lane >> 4;
    const int swz = lr & 7;

    const int bid = blockIdx.x;
    const int bh = bid >> 4, p = bid & 15;
    const int qt0 = p, qt1 = 31 - p;
    const int b = bh >> 4, h = bh & 15;
    const int kvh = h >> 2;

    const u16* Kp = Kb + (size_t)(b * NKV + kvh) * S_LEN * DHEAD;
    const u16* Vp = Vt + (size_t)(b * NKV + kvh) * DHEAD * S_LEN;

    short8 qf0[4], qf1[4];
    auto load_rope_q = [&](int qt, short8 (&qf)[4]) {
        const u16* Qp = Qb + ((size_t)((b * NH + h) * S_LEN) + qt * 64 + wave * 16) * DHEAD;
#pragma unroll
        for (int kk = 0; kk < 4; ++kk)
            qf[kk] = *(const short8*)(Qp + (size_t)lr * DHEAD + kk * 32 + q * 8);
        const int srow = qt * 64 + wave * 16 + lr;
        const int pp = pos[b * S_LEN + srow];
#pragma unroll
        for (int kk = 0; kk < 2; ++kk)
#pragma unroll
            for (int h4 = 0; h4 < 2; ++h4) {
                float4 cs = cs_tab[pp * 16 + kk * 8 + q * 2 + h4];
                float4 sn = sn_tab[pp * 16 + kk * 8 + q * 2 + h4];
#pragma unroll
                for (int e = 0; e < 4; ++e) {
                    float cc = (&cs.x)[e], ss = (&sn.x)[e];
                    int ei = h4 * 4 + e;
                    float x1 = bf2f((u16)qf[kk][ei]);
                    float x2 = bf2f((u16)qf[kk + 2][ei]);
                    qf[kk][ei]     = (short)f2bf(x1 * cc - x2 * ss);
                    qf[kk + 2][ei] = (short)f2bf(x2 * cc + x1 * ss);
                }
            }
    };
    load_rope_q(qt0, qf0);
    load_rope_q(qt1, qf1);

    auto stage = [&](int kt, int bs) {
#pragma unroll
        for (int i = 0; i < 4; ++i) {
            int ci = i * 256 + t;
            int krow = ci >> 4, kc = ((ci & 15) ^ ((ci >> 4) & 7)) << 3;
            async16(Kp + (size_t)(kt * 64 + krow) * DHEAD + kc,
                    &ldsK[bs][(i * 256 + wave * 64) * 8]);
            int dh = ci >> 3, vc = ((ci & 7) ^ ((ci >> 3) & 7)) << 3;
            async16(Vp + (size_t)dh * S_LEN + kt * 64 + vc,
                    &ldsV[bs][(i * 256 + wave * 64) * 8]);
        }
    };

    floatx4 accO[8];
    float m_i, l_i;

    auto do_tile = [&](int kt, int qt_c, const short8 (&qfc)[4], int bs) {
        floatx4 sc[4];
        __builtin_amdgcn_s_setprio(1);
#pragma unroll
        for (int c = 0; c < 4; ++c) {
            sc[c] = zf4();
#pragma unroll
            for (int kk = 0; kk < 4; ++kk) {
                short8 kfr = *(const short8*)(&ldsK[bs][(c * 16 + lr) * DHEAD +
                                              (((kk * 4 + q) ^ swz) << 3)]);
                sc[c] = mfma16(kfr, qfc[kk], sc[c]);
            }
        }
        __builtin_amdgcn_s_setprio(0);

        if (kt == qt_c) {
            const int qrow = wave * 16 + lr;
#pragma unroll
            for (int c = 0; c < 4; ++c)
#pragma unroll
                for (int rr = 0; rr < 4; ++rr)
                    if (c * 16 + q * 4 + rr > qrow) sc[c][rr] = -3e38f;
        }

        float mx = -3e38f;
#pragma unroll
        for (int c = 0; c < 4; ++c)
#pragma unroll
            for (int rr = 0; rr < 4; ++rr) mx = fmaxf(mx, sc[c][rr]);
        mx = fmaxf(mx, __shfl_xor(mx, 16));
        mx = fmaxf(mx, __shfl_xor(mx, 32));
        float mnew = fmaxf(m_i, mx);
        float mk = mnew * K2;
        bool anyup = __any(mnew > m_i);
        float rs = 0.f;
#pragma unroll
        for (int c = 0; c < 4; ++c)
#pragma unroll
            for (int rr = 0; rr < 4; ++rr) {
                float pe = __builtin_amdgcn_exp2f(fmaf(sc[c][rr], K2, -mk));
                sc[c][rr] = pe;
                rs += pe;
            }
        rs += __shfl_xor(rs, 16);
        rs += __shfl_xor(rs, 32);
        if (anyup) {
            float alpha = __builtin_amdgcn_exp2f(fmaf(m_i, K2, -mk));
            l_i = l_i * alpha + rs;
#pragma unroll
            for (int d = 0; d < 8; ++d) accO[d] *= alpha;
        } else {
            l_i += rs;
        }
        m_i = mnew;

        short4v pb[4];
#pragma unroll
        for (int c = 0; c < 4; ++c) {
            pb[c][0] = (short)f2bfr(sc[c][0]);
            pb[c][1] = (short)f2bfr(sc[c][1]);
            pb[c][2] = (short)f2bfr(sc[c][2]);
            pb[c][3] = (short)f2bfr(sc[c][3]);
        }

        __builtin_amdgcn_s_setprio(1);
#pragma unroll
        for (int ks = 0; ks < 4; ++ks)
#pragma unroll
            for (int d = 0; d < 8; ++d) {
                short4v vf = *(const short4v*)(&ldsV[bs][(d * 16 + lr) * 64 +
                                               (((ks * 2 + (q >> 1)) ^ swz) << 3) +
                                               (((q ^ (lr >> 3)) & 1) << 2)]);
                accO[d] = mfma16k16(vf, pb[ks], accO[d]);
            }
        __builtin_amdgcn_s_setprio(0);
    };

    auto epilogue = [&](int qt_c) {
        const int tok = qt_c * 64 + wave * 16 + lr;
        const float inv = 1.0f / l_i;
        u16* orow = Ob + ((size_t)(b * S_LEN + tok)) * (NH * DHEAD) + h * DHEAD + q * 4;
#pragma unroll
        for (int d = 0; d < 8; ++d) {
            ushort4 o;
            o.x = f2bf(accO[d][0] * inv);
            o.y = f2bf(accO[d][1] * inv);
            o.z = f2bf(accO[d][2] * inv);
            o.w = f2bf(accO[d][3] * inv);
            *(ushort4*)(orow + d * 16) = o;
        }
    };

#pragma unroll
    for (int d = 0; d < 8; ++d) accO[d] = zf4();
    m_i = -3e38f; l_i = 0.f;

    int cur = 0;
    stage(0, 0);
    __syncthreads();

    for (int kt = 0; kt <= qt0; ++kt) {
        int nxt = cur ^ 1;
        int nk = (kt < qt0) ? kt + 1 : 0;  // last tile prefetches seg-1 kt=0
        stage(nk, nxt);
        do_tile(kt, qt0, qf0, cur);
        __syncthreads();
        cur = nxt;
    }
    epilogue(qt0);
#pragma unroll
    for (int d = 0; d < 8; ++d) accO[d] = zf4();
    m_i = -3e38f; l_i = 0.f;

    for (int kt = 0; kt <= qt1; ++kt) {
        int nxt = cur ^ 1;
        if (kt < qt1) stage(kt + 1, nxt);
        do_tile(kt, qt1, qf1, cur);
        __syncthreads();
        cur = nxt;
    }
    epilogue(qt1);
}

extern "C" void kernel_launch(void* const* d_in, const int* in_sizes, int n_in,
                              void* d_out, int out_size, void* d_ws, size_t ws_size,
                              hipStream_t stream) {
    const float* X  = (const float*)d_in[0];
    const int* pos  = (const int*)d_in[1];
    const float* wq = (const float*)d_in[2];
    const float* wk = (const float*)d_in[3];
    const float* wv = (const float*)d_in[4];
    const float* wo = (const float*)d_in[5];
    float* out = (float*)d_out;

    char* w = (char*)d_ws;
    u16* Xbf    = (u16*)(w);                    // 4096*2048*2      = 16777216
    u16* Wqkv   = (u16*)(w + 16777216);         // 3072*2048*2      = 12582912
    u16* Wo     = (u16*)(w + 29360128);         // 2048*2048*2      =  8388608
    u16* Qb     = (u16*)(w + 37748736);         // 2*16*2048*128*2  = 16777216
    u16* Kb     = (u16*)(w + 54525952);         // 2*4*2048*128*2   =  4194304
    u16* Vt     = (u16*)(w + 58720256);         //                  =  4194304
    u16* Ob     = (u16*)(w + 62914560);         // 4096*2048*2      = 16777216
    float* cst  = (float*)(w + 79691776);       // 2048*64*4        =   524288
    float* snt  = (float*)(w + 80216064);       //                  =   524288

    prologue_kernel<<<18944, 256, 0, stream>>>((const float4*)X, (ushort4*)Xbf, cst, snt,
                                               wq, wk, wv, wo, Wqkv, Wo);
    qkv_gemm_kernel<<<768, 256, 0, stream>>>(Xbf, Wqkv, Qb, Kb, Vt);
    rope_k_kernel<<<1024, 256, 0, stream>>>(Kb, pos, (const float4*)cst, (const float4*)snt);
    fa_kernel<<<512, 256, 0, stream>>>(Qb, Kb, Vt, Ob, pos, (const float4*)cst, (const float4*)snt);
    out_gemm_kernel<<<512, 256, 0, stream>>>(Ob, Wo, out);
}